// Round 13
// baseline (247.437 us; speedup 1.0000x reference)
//
#include <hip/hip_runtime.h>
#include <hip/hip_fp16.h>

#define N_NODES  50000
#define N_EDGES  640000
#define N_GRAPHS 500
static constexpr float BN_EPS = 1e-5f;
#define SCAN_NB ((N_NODES + 255) / 256)   // 196 blocks
static constexpr float FIX = 16777216.0f;       // 2^24
static constexpr float FIXINV = 5.9604644775390625e-8f;  // 2^-24
static constexpr float Q16 = 65535.0f;
static constexpr float Q16INV = 1.0f / 65535.0f;

typedef _Float16 f16x8 __attribute__((ext_vector_type(8)));
typedef float f32x4 __attribute__((ext_vector_type(4)));

// csr entry: (src<<16) | round(norm*65535). src<50000<2^16; norm<1.
__device__ __forceinline__ float dec_nm(unsigned e) {
    return (float)(e & 0xFFFFu) * Q16INV;
}

// ---------------------------------------------------------------------------
// Packed degree accumulation: one 64-bit atomic per edge (count<<32 | wsum).
// R13: no seq output — edge rank is generated in k_fill via cursor atomics.
__global__ void k_degcnt(const int* __restrict__ dst, const float* __restrict__ w,
                         unsigned long long* __restrict__ packed, int E) {
    int i = blockIdx.x * blockDim.x + threadIdx.x;
    if (i < E) {
        int d = dst[i];
        unsigned uf = (unsigned)(w[i] * FIX + 0.5f);
        atomicAdd(&packed[d], (1ULL << 32) | (unsigned long long)uf);
    }
}

// ---------------------------------------------------------------------------
// Fused single-kernel exclusive scan (decoupled lookback) + dinv + goffs +
// bnprep (vbid 0) + W3 frag pre-swizzle (vbid 1) + W2 frag pre-swizzle
// (vbid 2). 196 blocks co-resident; ticket ordering -> only spin on
// already-resident earlier blocks. R13: also writes cursor[] (= offs copy)
// for k_fill's atomic rank generation.
static constexpr unsigned long long FLAG_AGG = 1ULL << 62;
static constexpr unsigned long long FLAG_INC = 2ULL << 62;

__global__ __launch_bounds__(256) void k_scanF(
    const unsigned long long* __restrict__ packed,
    unsigned long long* __restrict__ state, unsigned* __restrict__ ticket,
    int* __restrict__ offs, int* __restrict__ cursor, float* __restrict__ dinv,
    const int* __restrict__ batch, int* __restrict__ goffs,
    const float* W1,
    const float* b1, const float* g1, const float* be1, const float* m1, const float* v1,
    const float* b2, const float* g2, const float* be2, const float* m2, const float* v2,
    const float* b3, const float* g3, const float* be3, const float* m3, const float* v3,
    float* kA1, float* kB1, float* kA2, float* kB2, float* kA3, float* kB3,
    const float* __restrict__ W3, __half* __restrict__ W3s,
    const float* __restrict__ W2, __half* __restrict__ W2s,
    int n) {
    __shared__ int vbid_sh;
    __shared__ int part[256];
    __shared__ int prefix_sh;
    int t = threadIdx.x;
    if (t == 0) vbid_sh = (int)atomicAdd(ticket, 1u);
    __syncthreads();
    int vbid = vbid_sh;
    int i = vbid * 256 + t;
    unsigned long long pk = (i < n) ? packed[i] : 0ULL;
    int cnt = (int)(pk >> 32);
    part[t] = cnt;
    __syncthreads();
    for (int off = 1; off < 256; off <<= 1) {
        int u = (t >= off) ? part[t - off] : 0;
        __syncthreads();
        part[t] += u;
        __syncthreads();
    }
    int total = part[255];
    if (t < 64) {
        if (vbid == 0) {
            if (t == 0) {
                __hip_atomic_store(&state[0], FLAG_INC | (unsigned long long)(unsigned)total,
                                   __ATOMIC_RELEASE, __HIP_MEMORY_SCOPE_AGENT);
                prefix_sh = 0;
            }
        } else {
            if (t == 0)
                __hip_atomic_store(&state[vbid], FLAG_AGG | (unsigned long long)(unsigned)total,
                                   __ATOMIC_RELEASE, __HIP_MEMORY_SCOPE_AGENT);
            int run = 0;
            int base = vbid - 1;
            while (true) {
                int j = base - t;
                unsigned long long s;
                if (j >= 0) {
                    s = __hip_atomic_load(&state[j], __ATOMIC_ACQUIRE, __HIP_MEMORY_SCOPE_AGENT);
                    while (s == 0)
                        s = __hip_atomic_load(&state[j], __ATOMIC_ACQUIRE, __HIP_MEMORY_SCOPE_AGENT);
                } else {
                    s = FLAG_INC;   // virtual inclusive prefix 0 below block 0
                }
                bool inc = (s & FLAG_INC) != 0;
                int val = (int)(unsigned)(s & 0xFFFFFFFFULL);
                unsigned long long bal = __ballot(inc);
                int lim = (bal == 0) ? 63 : (int)__builtin_ctzll(bal);
                int contrib = (t <= lim) ? val : 0;
                for (int o = 1; o < 64; o <<= 1) contrib += __shfl_xor(contrib, o);
                run += contrib;
                if (bal != 0) break;
                base -= 64;
            }
            if (t == 0) {
                __hip_atomic_store(&state[vbid],
                                   FLAG_INC | (unsigned long long)(unsigned)(run + total),
                                   __ATOMIC_RELEASE, __HIP_MEMORY_SCOPE_AGENT);
                prefix_sh = run;
            }
        }
    }
    __syncthreads();
    int excl = prefix_sh + part[t] - cnt;
    if (i < n) {
        offs[i] = excl;
        cursor[i] = excl;           // k_fill's atomic rank counter
        float wdeg = (float)(unsigned)(pk & 0xFFFFFFFFu) * FIXINV;
        dinv[i] = rsqrtf(wdeg + 1.0f);
    }
    if (i == n - 1) offs[n] = N_EDGES;
    // graph range precompute: goffs[g] = lower_bound(batch, g)
    if (i <= N_GRAPHS) {
        int lo = 0, hi = n;
        while (lo < hi) { int m = (lo + hi) >> 1; if (batch[m] < i) lo = m + 1; else hi = m; }
        goffs[i] = lo;
    }
    // bnprep (block 0 only; independent of scan data)
    if (vbid == 0) {
        if (t < 64) {
            float s = g1[t] * rsqrtf(v1[t] + BN_EPS);
            kA1[t] = W1[t] * s;
            kB1[t] = (b1[t] - m1[t]) * s + be1[t];
        }
        if (t < 128) {
            float s2 = g2[t] * rsqrtf(v2[t] + BN_EPS);
            kA2[t] = s2; kB2[t] = (b2[t] - m2[t]) * s2 + be2[t];
            float s3 = g3[t] * rsqrtf(v3[t] + BN_EPS);
            kA3[t] = s3; kB3[t] = (b3[t] - m3[t]) * s3 + be3[t];
        }
    }
    // W3 fp16 B-fragment pre-swizzle (vbid 1): W3s[nt][ks][lane][8] =
    // W3[ks*32 + (lane>>4)*8 + j][nt*16 + (lane&15)]
    if (vbid == 1) {
        for (int idx = t; idx < 2048; idx += 256) {
            int nt = idx >> 8;
            int ks = (idx >> 6) & 3;
            int lane = idx & 63;
            int col = nt * 16 + (lane & 15);
            int kb = ks * 32 + (lane >> 4) * 8;
            uint4 uv;
            unsigned* up = &uv.x;
            for (int j2 = 0; j2 < 4; ++j2) {
                __half2 p = __floats2half2_rn(W3[(size_t)(kb + 2 * j2) * 128 + col],
                                              W3[(size_t)(kb + 2 * j2 + 1) * 128 + col]);
                up[j2] = *(unsigned*)&p;
            }
            *(uint4*)(W3s + (size_t)idx * 8) = uv;
        }
    }
    // W2 fp16 B-fragment pre-swizzle (vbid 2): K=64 -> 2 k-steps.
    if (vbid == 2) {
        for (int idx = t; idx < 1024; idx += 256) {
            int nt = idx >> 7;
            int ks = (idx >> 6) & 1;
            int lane = idx & 63;
            int col = nt * 16 + (lane & 15);
            int kb = ks * 32 + (lane >> 4) * 8;
            uint4 uv;
            unsigned* up = &uv.x;
            for (int j2 = 0; j2 < 4; ++j2) {
                __half2 p = __floats2half2_rn(W2[(size_t)(kb + 2 * j2) * 128 + col],
                                              W2[(size_t)(kb + 2 * j2 + 1) * 128 + col]);
                up[j2] = *(unsigned*)&p;
            }
            *(uint4*)(W2s + (size_t)idx * 8) = uv;
        }
    }
}

// CSR fill with cursor-atomic rank: pos = atomicAdd(&cursor[d],1).
// Placement order within a node's list is nondeterministic — it already was
// (rank came from degcnt's atomic order). (R1 lesson still honored: no fp32
// value atomics, no extra gathers.)
__global__ void k_fill(const int* __restrict__ src, const int* __restrict__ dst,
                       const float* __restrict__ w, const float* __restrict__ dinv,
                       int* __restrict__ cursor,
                       unsigned* __restrict__ csr, int E) {
    int e = blockIdx.x * blockDim.x + threadIdx.x;
    if (e < E) {
        int s = src[e], d = dst[e];
        float nm = dinv[s] * w[e] * dinv[d];
        unsigned q = (unsigned)(nm * Q16 + 0.5f);
        q = (q > 65535u) ? 65535u : q;
        int pos = atomicAdd(&cursor[d], 1);
        csr[pos] = ((unsigned)s << 16) | q;
    }
}

// Layer-1 aggregation, 4 lanes/node + xor-butterfly. Writes plain fp32 aggx
// (200KB — L1/L2-hot for the layer-2 gather). [R8: 8 lanes past the knee.]
__global__ void k_aggx(const int* __restrict__ offs, const unsigned* __restrict__ csr,
                       const float* __restrict__ x, const float* __restrict__ dinv,
                       float* __restrict__ aggx, int n) {
    int gid = blockIdx.x * blockDim.x + threadIdx.x;
    int node = gid >> 2;
    if (node >= n) return;
    int sub = gid & 3;
    float acc = 0.f;
    int e0 = offs[node], e1 = offs[node + 1];
    for (int j = e0 + sub; j < e1; j += 4) {
        unsigned e = csr[j];
        acc += x[e >> 16] * dec_nm(e);
    }
    acc += __shfl_xor(acc, 1);
    acc += __shfl_xor(acc, 2);
    if (sub == 0) {
        float di = dinv[node];
        aggx[node] = acc + x[node] * di * di;
    }
}

// ---------------------------------------------------------------------------
// Layer-2 aggregation from the SCALAR aggx (L2-hot), in-register h1 per edge
// (R10-proven form — R12's shfl distribution was null, reverted).
// 8 thr/node: 4 q x 2 parity (chain ~6.4); each thread owns 16 channels.
__global__ void k_gather2A(const int* __restrict__ offs, const unsigned* __restrict__ csr,
                           const float* __restrict__ aggx, const float* __restrict__ dinv,
                           const float* __restrict__ kA1, const float* __restrict__ kB1,
                           __half* __restrict__ aggs, int n) {
    int tid = threadIdx.x;
    int node = blockIdx.x * 32 + (tid >> 3);
    if (node >= n) return;
    int q = tid & 3;
    int par = (tid >> 2) & 1;
    int c0 = q * 8;
    float wa[16], wb[16];
#pragma unroll
    for (int c = 0; c < 8; ++c) {
        wa[c] = kA1[c0 + c];          wb[c] = kB1[c0 + c];
        wa[8 + c] = kA1[c0 + 32 + c]; wb[8 + c] = kB1[c0 + 32 + c];
    }
    float acc[16];
#pragma unroll
    for (int c = 0; c < 16; ++c) acc[c] = 0.f;
    int e0 = offs[node], e1 = offs[node + 1];
    int j = e0 + par;
    // 2-edge step within this parity stream (stride 2)
    for (; j + 2 < e1; j += 4) {
        unsigned ea = csr[j];
        unsigned eb = csr[j + 2];
        float aa = aggx[ea >> 16];
        float ab = aggx[eb >> 16];
        float na = dec_nm(ea);
        float nb = dec_nm(eb);
#pragma unroll
        for (int c = 0; c < 16; ++c) {
            acc[c] += na * fmaxf(aa * wa[c] + wb[c], 0.f);
            acc[c] += nb * fmaxf(ab * wa[c] + wb[c], 0.f);
        }
    }
    for (; j < e1; j += 2) {
        unsigned e = csr[j];
        float a = aggx[e >> 16];
        float nm = dec_nm(e);
#pragma unroll
        for (int c = 0; c < 16; ++c)
            acc[c] += nm * fmaxf(a * wa[c] + wb[c], 0.f);
    }
    // combine the two parity streams (bit 2 of tid)
#pragma unroll
    for (int c = 0; c < 16; ++c) acc[c] += __shfl_xor(acc[c], 4);
    if (par == 0) {
        float di = dinv[node];
        float d2 = di * di;
        float a = aggx[node];
#pragma unroll
        for (int c = 0; c < 16; ++c)
            acc[c] += d2 * fmaxf(a * wa[c] + wb[c], 0.f);
        uint4 o0, o1;
        unsigned* p0 = &o0.x;
        unsigned* p1 = &o1.x;
#pragma unroll
        for (int j2 = 0; j2 < 4; ++j2) {
            __half2 q0 = __floats2half2_rn(acc[2 * j2], acc[2 * j2 + 1]);
            __half2 q1 = __floats2half2_rn(acc[8 + 2 * j2], acc[8 + 2 * j2 + 1]);
            p0[j2] = *(unsigned*)&q0;
            p1[j2] = *(unsigned*)&q1;
        }
        *(uint4*)(aggs + (size_t)node * 32 + c0) = o0;                          // slice 0
        *(uint4*)(aggs + (size_t)n * 32 + (size_t)node * 32 + c0) = o1;         // slice 1
    }
}

// ---------------------------------------------------------------------------
// Channel-sliced gather from an fp16 node-major-32 table (R4 layout: one
// fully-utilized 64B line per edge per slice). SLB = log2(#slices).
// R10-proven form: 8 thr/node, 4 q x 2 parity, 4/2/1-edge unroll ladder.
template <int SLB>
__global__ void k_gatherS(const int* __restrict__ offs, const unsigned* __restrict__ csr,
                          const __half* __restrict__ Hh, const float* __restrict__ dinv,
                          __half* __restrict__ aggs, int n) {
    int slice = blockIdx.x & ((1 << SLB) - 1);
    int tid = threadIdx.x;
    int node = (blockIdx.x >> SLB) * 32 + (tid >> 3);
    if (node >= n) return;
    int q = tid & 3;
    int par = (tid >> 2) & 1;
    const __half* Hb = Hh + (size_t)slice * ((size_t)n * 32) + q * 8;
    float acc[8] = {0.f, 0.f, 0.f, 0.f, 0.f, 0.f, 0.f, 0.f};
    int e0 = offs[node], e1 = offs[node + 1];
    int j = e0 + par;
#define GS_LOAD(ev, rawv) uint4 rawv = *(const uint4*)(Hb + (size_t)((ev) >> 16) * 32)
#define GS_ACC(rawv, nmv) { \
        __half2 h0 = *(__half2*)&rawv.x; __half2 h1 = *(__half2*)&rawv.y; \
        __half2 h2 = *(__half2*)&rawv.z; __half2 h3 = *(__half2*)&rawv.w; \
        float2 f0 = __half22float2(h0); float2 f1 = __half22float2(h1); \
        float2 f2 = __half22float2(h2); float2 f3 = __half22float2(h3); \
        acc[0] += f0.x * nmv; acc[1] += f0.y * nmv; \
        acc[2] += f1.x * nmv; acc[3] += f1.y * nmv; \
        acc[4] += f2.x * nmv; acc[5] += f2.y * nmv; \
        acc[6] += f3.x * nmv; acc[7] += f3.y * nmv; }
    // 4-edge unroll within this parity stream (stride 2)
    for (; j + 6 < e1; j += 8) {
        unsigned e_0 = csr[j];
        unsigned e_1 = csr[j + 2];
        unsigned e_2 = csr[j + 4];
        unsigned e_3 = csr[j + 6];
        GS_LOAD(e_0, r0); GS_LOAD(e_1, r1); GS_LOAD(e_2, r2); GS_LOAD(e_3, r3);
        GS_ACC(r0, dec_nm(e_0)); GS_ACC(r1, dec_nm(e_1));
        GS_ACC(r2, dec_nm(e_2)); GS_ACC(r3, dec_nm(e_3));
    }
    // 2-edge step (common case for the ~6.4-edge streams)
    for (; j + 2 < e1; j += 4) {
        unsigned e_0 = csr[j];
        unsigned e_1 = csr[j + 2];
        GS_LOAD(e_0, r0); GS_LOAD(e_1, r1);
        GS_ACC(r0, dec_nm(e_0)); GS_ACC(r1, dec_nm(e_1));
    }
    for (; j < e1; j += 2) {
        unsigned e = csr[j];
        GS_LOAD(e, rr);
        GS_ACC(rr, dec_nm(e));
    }
    // combine the two parity streams (bit 2 of tid)
#pragma unroll
    for (int k = 0; k < 8; ++k) acc[k] += __shfl_xor(acc[k], 4);
    if (par == 0) {
        float di = dinv[node];
        float d2 = di * di;
        GS_LOAD((unsigned)node << 16, rs);
        GS_ACC(rs, d2);
        uint4 ov;
        unsigned* op4 = &ov.x;
#pragma unroll
        for (int j2 = 0; j2 < 4; ++j2) {
            __half2 p = __floats2half2_rn(acc[2 * j2], acc[2 * j2 + 1]);
            op4[j2] = *(unsigned*)&p;
        }
        *(uint4*)(aggs + (size_t)slice * ((size_t)n * 32) + (size_t)node * 32 + q * 8) = ov;
    }
#undef GS_LOAD
#undef GS_ACC
}

// ---------------------------------------------------------------------------
// MFMA matmul (f16 16x16x32): 64 nodes/block, 4 waves, wave = one 16-node
// m-tile x all 8 ch-tiles, K = KS*32. A-frags direct from the gather table
// ([kstep][node][32]); B-frags pre-swizzled. C/D: col=lane&15,
// row=(lane>>4)*4+reg [HW-verified, R5]. BN+ReLU epilogue; per-graph pooling
// into sums. WRT=1 additionally writes the fp16 node-major-32 table (layer 2).
template <int KS, int WRT>
__global__ __launch_bounds__(256) void k_mmF(
    const __half* __restrict__ aggs, const __half* __restrict__ Ws,
    const float* __restrict__ kA, const float* __restrict__ kB,
    const int* __restrict__ batch, float* __restrict__ sums,
    __half* __restrict__ outh, int n) {
    const size_t N32 = (size_t)n * 32;
    int base = blockIdx.x * 64;
    int tid = threadIdx.x;
    int w = tid >> 6;
    int l = tid & 63;
    int lr = l & 15;
    int lg = l >> 4;
    int anode = base + w * 16 + lr;
    if (anode > n - 1) anode = n - 1;   // clamped (OOB rows excluded below)
    const __half* ap = aggs + (size_t)anode * 32 + lg * 8;
    f16x8 afr[KS];
#pragma unroll
    for (int ks = 0; ks < KS; ++ks)
        afr[ks] = *(const f16x8*)(ap + (size_t)ks * N32);

    const f16x8* Wv = (const f16x8*)Ws;
    f32x4 acc[8];
#pragma unroll
    for (int nt = 0; nt < 8; ++nt) acc[nt] = (f32x4){0.f, 0.f, 0.f, 0.f};
#pragma unroll
    for (int nt = 0; nt < 8; ++nt) {
#pragma unroll
        for (int ks = 0; ks < KS; ++ks) {
            f16x8 bfr = Wv[(size_t)(nt * KS + ks) * 64 + l];
            acc[nt] = __builtin_amdgcn_mfma_f32_16x16x32_f16(afr[ks], bfr, acc[nt], 0, 0, 0);
        }
    }
    // epilogue: BN + ReLU
    int pnode0 = base + w * 16 + lg * 4;
    int bgv[4];
#pragma unroll
    for (int r = 0; r < 4; ++r) {
        int nd = pnode0 + r;
        bgv[r] = (nd < n) ? batch[nd] : -1;
    }
    float h[8][4];
#pragma unroll
    for (int nt = 0; nt < 8; ++nt) {
        int ch = nt * 16 + lr;
        float ka = kA[ch], kb = kB[ch];
#pragma unroll
        for (int r = 0; r < 4; ++r)
            h[nt][r] = fmaxf(acc[nt][r] * ka + kb, 0.f);
    }
    if (WRT) {
#pragma unroll
        for (int nt = 0; nt < 8; ++nt) {
            int ch = nt * 16 + lr;
            size_t sbase = (size_t)(ch >> 5) * N32 + (ch & 31);
#pragma unroll
            for (int r = 0; r < 4; ++r) {
                int nd = pnode0 + r;
                if (nd < n) outh[sbase + (size_t)nd * 32] = (__half)h[nt][r];
            }
        }
    }
    // per-graph pooling
    __shared__ float pred[4][128];
    int g0 = batch[base];
    int gl = batch[(base + 63 < n) ? (base + 63) : (n - 1)];
    for (int g = g0; g <= gl; ++g) {
        __syncthreads();
#pragma unroll
        for (int nt = 0; nt < 8; ++nt) {
            float s = 0.f;
#pragma unroll
            for (int r = 0; r < 4; ++r)
                if (bgv[r] == g) s += h[nt][r];
            s += __shfl_xor(s, 16);
            s += __shfl_xor(s, 32);
            if (l < 16) pred[w][nt * 16 + l] = s;
        }
        __syncthreads();
        if (tid < 128) {
            float tot = pred[0][tid] + pred[1][tid] + pred[2][tid] + pred[3][tid];
            atomicAdd(&sums[g * 128 + tid], tot);
        }
    }
}

// ---------------------------------------------------------------------------
// Finalize: out[g] = dot(sums[g]/cnt[g], Wf) + bf. 256KB read — trivial.
__global__ __launch_bounds__(128) void k_final(
    const float* __restrict__ sums, const int* __restrict__ goffs,
    const float* __restrict__ Wf, const float* __restrict__ bf,
    float* __restrict__ out) {
    int g = blockIdx.x;
    int t = threadIdx.x;
    float v = sums[g * 128 + t] * Wf[t];
    for (int o = 32; o > 0; o >>= 1) v += __shfl_down(v, o);
    __shared__ float r[2];
    if (t == 0) r[0] = v;
    if (t == 64) r[1] = v;
    __syncthreads();
    if (t == 0) {
        int cnt = goffs[g + 1] - goffs[g];
        out[g] = (r[0] + r[1]) / fmaxf((float)cnt, 1.f) + bf[0];
    }
}

// ---------------------------------------------------------------------------
extern "C" void kernel_launch(void* const* d_in, const int* in_sizes, int n_in,
                              void* d_out, int out_size, void* d_ws, size_t ws_size,
                              hipStream_t stream) {
    const float* x     = (const float*)d_in[0];
    const int*   ei    = (const int*)d_in[1];
    const int*   src   = ei;
    const int*   dst   = ei + N_EDGES;
    const float* w     = (const float*)d_in[2];
    const int*   batch = (const int*)d_in[3];
    const float* W1 = (const float*)d_in[4];
    const float* b1 = (const float*)d_in[5];
    const float* W2 = (const float*)d_in[6];
    const float* b2 = (const float*)d_in[7];
    const float* W3 = (const float*)d_in[8];
    const float* b3 = (const float*)d_in[9];
    const float* Wf = (const float*)d_in[10];
    const float* bf = (const float*)d_in[11];
    const float* g1 = (const float*)d_in[12];
    const float* be1 = (const float*)d_in[13];
    const float* m1 = (const float*)d_in[14];
    const float* v1 = (const float*)d_in[15];
    const float* g2 = (const float*)d_in[16];
    const float* be2 = (const float*)d_in[17];
    const float* m2 = (const float*)d_in[18];
    const float* v2 = (const float*)d_in[19];
    const float* g3 = (const float*)d_in[20];
    const float* be3 = (const float*)d_in[21];
    const float* m3 = (const float*)d_in[22];
    const float* v3 = (const float*)d_in[23];

    float* out = (float*)d_out;

    // Workspace layout
    float* ws    = (float*)d_ws;
    float* buf2  = ws;                                    // N*128 fp32-sized region:
    __half* agg2h = (__half*)buf2;                        // N*64 fp16 (6.4MB)
    __half* aggsh = (__half*)((char*)buf2 + (size_t)N_NODES * 64 * 2);   // N*128 fp16 (12.8MB)
    unsigned* csr = (unsigned*)(buf2 + (size_t)N_NODES * 128); // E uint
    unsigned long long* packed = (unsigned long long*)(csr + N_EDGES); // N ull
    float* sums  = (float*)(packed + N_NODES);            // G*128
    unsigned long long* state = (unsigned long long*)(sums + N_GRAPHS * 128); // SCAN_NB ull
    unsigned* ticket = (unsigned*)(state + SCAN_NB);      // 4 uint (pad)
    int*   cursor = (int*)(ticket + 4);                   // N (replaces seq)
    float* dinv  = (float*)(cursor + N_NODES);            // N
    float* aggx  = dinv + N_NODES;                        // N fp32
    float* kA1   = aggx + N_NODES;                        // 64
    float* kB1   = kA1 + 64;                              // 64
    float* kA2   = kB1 + 64;                              // 128
    float* kB2   = kA2 + 128;                             // 128
    float* kA3   = kB2 + 128;                             // 128
    float* kB3   = kA3 + 128;                             // 128
    int*   offs  = (int*)(kB3 + 128);                     // N+1
    int*   goffs = offs + N_NODES + 1;                    // G+1 (+pad)
    // out2h: N*128 fp16 table, 64B-aligned so each 64B node-row is one line
    uintptr_t oh = (uintptr_t)(goffs + 505);
    oh = (oh + 63) & ~(uintptr_t)63;
    __half* out2h = (__half*)oh;                          // 12.8 MB
    __half* W3s   = out2h + (size_t)N_NODES * 128;        // 32 KB
    __half* W2s   = W3s + 2048 * 8;                       // 16 KB

    const int BS = 256;
    auto nb = [](long n) { return (int)((n + 255) / 256); };

    // zero packed + sums + state + ticket in one call (contiguous in ws)
    size_t ms_bytes = (size_t)N_NODES * 8 + (size_t)N_GRAPHS * 128 * 4
                    + (size_t)SCAN_NB * 8 + 16;
    hipMemsetAsync(packed, 0, ms_bytes, stream);

    // --- CSR build + degree norm (+goffs+bnprep+W2/W3 swizzle in scanF) ---
    k_degcnt<<<nb(N_EDGES), BS, 0, stream>>>(dst, w, packed, N_EDGES);
    k_scanF<<<SCAN_NB, 256, 0, stream>>>(packed, state, ticket, offs, cursor, dinv,
                                         batch, goffs,
                                         W1, b1, g1, be1, m1, v1, b2, g2, be2, m2, v2,
                                         b3, g3, be3, m3, v3,
                                         kA1, kB1, kA2, kB2, kA3, kB3,
                                         W3, W3s, W2, W2s, N_NODES);
    k_fill<<<nb(N_EDGES), BS, 0, stream>>>(src, dst, w, dinv, cursor, csr, N_EDGES);

    // --- Layer 1: aggregate (4 lanes/node) -> fp32 aggx (200KB, L2-hot) ---
    k_aggx<<<nb((long)N_NODES * 4), BS, 0, stream>>>(
        offs, csr, x, dinv, aggx, N_NODES);

    // --- Layer 2: scalar-aggx gather + in-reg h1 (8thr/node) -> fp16
    //     A-frags, MFMA matmul (out2h table + residual pool into sums) ---
    k_gather2A<<<(N_NODES + 31) / 32, BS, 0, stream>>>(
        offs, csr, aggx, dinv, kA1, kB1, agg2h, N_NODES);
    k_mmF<2, 1><<<(N_NODES + 63) / 64, BS, 0, stream>>>(
        agg2h, W2s, kA2, kB2, batch, sums, out2h, N_NODES);

    // --- Layer 3: gather out2h (4 slices, 8thr/node) -> fp16 A-frags,
    //     MFMA matmul + pool ---
    k_gatherS<2><<<4 * ((N_NODES + 31) / 32), BS, 0, stream>>>(
        offs, csr, out2h, dinv, aggsh, N_NODES);
    k_mmF<4, 0><<<(N_NODES + 63) / 64, BS, 0, stream>>>(
        aggsh, W3s, kA3, kB3, batch, sums, nullptr, N_NODES);

    // --- finalize: tiny dot-product over sums ---
    k_final<<<N_GRAPHS, 128, 0, stream>>>(sums, goffs, Wf, bf, out);
}

// Round 14
// 225.150 us; speedup vs baseline: 1.0990x; 1.0990x over previous
//
#include <hip/hip_runtime.h>
#include <hip/hip_fp16.h>

#define N_NODES  50000
#define N_EDGES  640000
#define N_GRAPHS 500
static constexpr float BN_EPS = 1e-5f;
#define SCAN_NB ((N_NODES + 255) / 256)   // 196 blocks
static constexpr float FIX = 16777216.0f;       // 2^24
static constexpr float FIXINV = 5.9604644775390625e-8f;  // 2^-24
static constexpr float Q16 = 65535.0f;
static constexpr float Q16INV = 1.0f / 65535.0f;

typedef _Float16 f16x8 __attribute__((ext_vector_type(8)));
typedef float f32x4 __attribute__((ext_vector_type(4)));

// csr entry: (src<<16) | round(norm*65535). src<50000<2^16; norm<1.
__device__ __forceinline__ float dec_nm(unsigned e) {
    return (float)(e & 0xFFFFu) * Q16INV;
}

// ---------------------------------------------------------------------------
// Packed degree/count: one 64-bit atomic per edge; old value -> seq[] rank.
// [R13 lesson: keep the rank HERE (fire-and-forget atomic + coalesced seq
//  write). Moving it to k_fill as a cursor atomic with a dependent scatter
//  store cost +20 µs — atomic-return + dependent consumer serializes.]
__global__ void k_degcnt(const int* __restrict__ dst, const float* __restrict__ w,
                         unsigned long long* __restrict__ packed,
                         int* __restrict__ seq, int E) {
    int i = blockIdx.x * blockDim.x + threadIdx.x;
    if (i < E) {
        int d = dst[i];
        unsigned uf = (unsigned)(w[i] * FIX + 0.5f);
        unsigned long long old =
            atomicAdd(&packed[d], (1ULL << 32) | (unsigned long long)uf);
        seq[i] = (int)(old >> 32);
    }
}

// ---------------------------------------------------------------------------
// Fused single-kernel exclusive scan (decoupled lookback) + dinv + goffs +
// bnprep (vbid 0) + W3 frag pre-swizzle (vbid 1) + W2 frag pre-swizzle
// (vbid 2). 196 blocks co-resident; ticket ordering -> only spin on
// already-resident earlier blocks.
static constexpr unsigned long long FLAG_AGG = 1ULL << 62;
static constexpr unsigned long long FLAG_INC = 2ULL << 62;

__global__ __launch_bounds__(256) void k_scanF(
    const unsigned long long* __restrict__ packed,
    unsigned long long* __restrict__ state, unsigned* __restrict__ ticket,
    int* __restrict__ offs, float* __restrict__ dinv,
    const int* __restrict__ batch, int* __restrict__ goffs,
    const float* W1,
    const float* b1, const float* g1, const float* be1, const float* m1, const float* v1,
    const float* b2, const float* g2, const float* be2, const float* m2, const float* v2,
    const float* b3, const float* g3, const float* be3, const float* m3, const float* v3,
    float* kA1, float* kB1, float* kA2, float* kB2, float* kA3, float* kB3,
    const float* __restrict__ W3, __half* __restrict__ W3s,
    const float* __restrict__ W2, __half* __restrict__ W2s,
    int n) {
    __shared__ int vbid_sh;
    __shared__ int part[256];
    __shared__ int prefix_sh;
    int t = threadIdx.x;
    if (t == 0) vbid_sh = (int)atomicAdd(ticket, 1u);
    __syncthreads();
    int vbid = vbid_sh;
    int i = vbid * 256 + t;
    unsigned long long pk = (i < n) ? packed[i] : 0ULL;
    int cnt = (int)(pk >> 32);
    part[t] = cnt;
    __syncthreads();
    for (int off = 1; off < 256; off <<= 1) {
        int u = (t >= off) ? part[t - off] : 0;
        __syncthreads();
        part[t] += u;
        __syncthreads();
    }
    int total = part[255];
    if (t < 64) {
        if (vbid == 0) {
            if (t == 0) {
                __hip_atomic_store(&state[0], FLAG_INC | (unsigned long long)(unsigned)total,
                                   __ATOMIC_RELEASE, __HIP_MEMORY_SCOPE_AGENT);
                prefix_sh = 0;
            }
        } else {
            if (t == 0)
                __hip_atomic_store(&state[vbid], FLAG_AGG | (unsigned long long)(unsigned)total,
                                   __ATOMIC_RELEASE, __HIP_MEMORY_SCOPE_AGENT);
            int run = 0;
            int base = vbid - 1;
            while (true) {
                int j = base - t;
                unsigned long long s;
                if (j >= 0) {
                    s = __hip_atomic_load(&state[j], __ATOMIC_ACQUIRE, __HIP_MEMORY_SCOPE_AGENT);
                    while (s == 0)
                        s = __hip_atomic_load(&state[j], __ATOMIC_ACQUIRE, __HIP_MEMORY_SCOPE_AGENT);
                } else {
                    s = FLAG_INC;   // virtual inclusive prefix 0 below block 0
                }
                bool inc = (s & FLAG_INC) != 0;
                int val = (int)(unsigned)(s & 0xFFFFFFFFULL);
                unsigned long long bal = __ballot(inc);
                int lim = (bal == 0) ? 63 : (int)__builtin_ctzll(bal);
                int contrib = (t <= lim) ? val : 0;
                for (int o = 1; o < 64; o <<= 1) contrib += __shfl_xor(contrib, o);
                run += contrib;
                if (bal != 0) break;
                base -= 64;
            }
            if (t == 0) {
                __hip_atomic_store(&state[vbid],
                                   FLAG_INC | (unsigned long long)(unsigned)(run + total),
                                   __ATOMIC_RELEASE, __HIP_MEMORY_SCOPE_AGENT);
                prefix_sh = run;
            }
        }
    }
    __syncthreads();
    int excl = prefix_sh + part[t] - cnt;
    if (i < n) {
        offs[i] = excl;
        float wdeg = (float)(unsigned)(pk & 0xFFFFFFFFu) * FIXINV;
        dinv[i] = rsqrtf(wdeg + 1.0f);
    }
    if (i == n - 1) offs[n] = N_EDGES;
    // graph range precompute: goffs[g] = lower_bound(batch, g)
    if (i <= N_GRAPHS) {
        int lo = 0, hi = n;
        while (lo < hi) { int m = (lo + hi) >> 1; if (batch[m] < i) lo = m + 1; else hi = m; }
        goffs[i] = lo;
    }
    // bnprep (block 0 only; independent of scan data)
    if (vbid == 0) {
        if (t < 64) {
            float s = g1[t] * rsqrtf(v1[t] + BN_EPS);
            kA1[t] = W1[t] * s;
            kB1[t] = (b1[t] - m1[t]) * s + be1[t];
        }
        if (t < 128) {
            float s2 = g2[t] * rsqrtf(v2[t] + BN_EPS);
            kA2[t] = s2; kB2[t] = (b2[t] - m2[t]) * s2 + be2[t];
            float s3 = g3[t] * rsqrtf(v3[t] + BN_EPS);
            kA3[t] = s3; kB3[t] = (b3[t] - m3[t]) * s3 + be3[t];
        }
    }
    // W3 fp16 B-fragment pre-swizzle (vbid 1): W3s[nt][ks][lane][8] =
    // W3[ks*32 + (lane>>4)*8 + j][nt*16 + (lane&15)]
    if (vbid == 1) {
        for (int idx = t; idx < 2048; idx += 256) {
            int nt = idx >> 8;
            int ks = (idx >> 6) & 3;
            int lane = idx & 63;
            int col = nt * 16 + (lane & 15);
            int kb = ks * 32 + (lane >> 4) * 8;
            uint4 uv;
            unsigned* up = &uv.x;
            for (int j2 = 0; j2 < 4; ++j2) {
                __half2 p = __floats2half2_rn(W3[(size_t)(kb + 2 * j2) * 128 + col],
                                              W3[(size_t)(kb + 2 * j2 + 1) * 128 + col]);
                up[j2] = *(unsigned*)&p;
            }
            *(uint4*)(W3s + (size_t)idx * 8) = uv;
        }
    }
    // W2 fp16 B-fragment pre-swizzle (vbid 2): K=64 -> 2 k-steps.
    if (vbid == 2) {
        for (int idx = t; idx < 1024; idx += 256) {
            int nt = idx >> 7;
            int ks = (idx >> 6) & 1;
            int lane = idx & 63;
            int col = nt * 16 + (lane & 15);
            int kb = ks * 32 + (lane >> 4) * 8;
            uint4 uv;
            unsigned* up = &uv.x;
            for (int j2 = 0; j2 < 4; ++j2) {
                __half2 p = __floats2half2_rn(W2[(size_t)(kb + 2 * j2) * 128 + col],
                                              W2[(size_t)(kb + 2 * j2 + 1) * 128 + col]);
                up[j2] = *(unsigned*)&p;
            }
            *(uint4*)(W2s + (size_t)idx * 8) = uv;
        }
    }
}

// Atomic-free CSR fill: pos = offs[dst] + seq[e]. 4-byte packed entry.
// (R1/R13 lessons: no per-edge value atomics, no cursor atomics here.)
__global__ void k_fill(const int* __restrict__ src, const int* __restrict__ dst,
                       const float* __restrict__ w, const float* __restrict__ dinv,
                       const int* __restrict__ offs, const int* __restrict__ seq,
                       unsigned* __restrict__ csr, int E) {
    int e = blockIdx.x * blockDim.x + threadIdx.x;
    if (e < E) {
        int s = src[e], d = dst[e];
        int pos = offs[d] + seq[e];
        float nm = dinv[s] * w[e] * dinv[d];
        unsigned q = (unsigned)(nm * Q16 + 0.5f);
        q = (q > 65535u) ? 65535u : q;
        csr[pos] = ((unsigned)s << 16) | q;
    }
}

// Layer-1 aggregation, 4 lanes/node + xor-butterfly. Writes plain fp32 aggx
// (200KB — L1/L2-hot for the layer-2 gather). [R8: 8 lanes past the knee.]
__global__ void k_aggx(const int* __restrict__ offs, const unsigned* __restrict__ csr,
                       const float* __restrict__ x, const float* __restrict__ dinv,
                       float* __restrict__ aggx, int n) {
    int gid = blockIdx.x * blockDim.x + threadIdx.x;
    int node = gid >> 2;
    if (node >= n) return;
    int sub = gid & 3;
    float acc = 0.f;
    int e0 = offs[node], e1 = offs[node + 1];
    for (int j = e0 + sub; j < e1; j += 4) {
        unsigned e = csr[j];
        acc += x[e >> 16] * dec_nm(e);
    }
    acc += __shfl_xor(acc, 1);
    acc += __shfl_xor(acc, 2);
    if (sub == 0) {
        float di = dinv[node];
        aggx[node] = acc + x[node] * di * di;
    }
}

// ---------------------------------------------------------------------------
// Layer-2 aggregation from the SCALAR aggx (L2-hot), in-register h1 per edge
// (R10-proven: 200KB scalar operand beats 6.4MB table; ReLU latency-hidden).
// 8 thr/node: 4 q x 2 parity (chain ~6.4); each thread owns 16 channels.
__global__ void k_gather2A(const int* __restrict__ offs, const unsigned* __restrict__ csr,
                           const float* __restrict__ aggx, const float* __restrict__ dinv,
                           const float* __restrict__ kA1, const float* __restrict__ kB1,
                           __half* __restrict__ aggs, int n) {
    int tid = threadIdx.x;
    int node = blockIdx.x * 32 + (tid >> 3);
    if (node >= n) return;
    int q = tid & 3;
    int par = (tid >> 2) & 1;
    int c0 = q * 8;
    float wa[16], wb[16];
#pragma unroll
    for (int c = 0; c < 8; ++c) {
        wa[c] = kA1[c0 + c];          wb[c] = kB1[c0 + c];
        wa[8 + c] = kA1[c0 + 32 + c]; wb[8 + c] = kB1[c0 + 32 + c];
    }
    float acc[16];
#pragma unroll
    for (int c = 0; c < 16; ++c) acc[c] = 0.f;
    int e0 = offs[node], e1 = offs[node + 1];
    int j = e0 + par;
    // 2-edge step within this parity stream (stride 2)
    for (; j + 2 < e1; j += 4) {
        unsigned ea = csr[j];
        unsigned eb = csr[j + 2];
        float aa = aggx[ea >> 16];
        float ab = aggx[eb >> 16];
        float na = dec_nm(ea);
        float nb = dec_nm(eb);
#pragma unroll
        for (int c = 0; c < 16; ++c) {
            acc[c] += na * fmaxf(aa * wa[c] + wb[c], 0.f);
            acc[c] += nb * fmaxf(ab * wa[c] + wb[c], 0.f);
        }
    }
    for (; j < e1; j += 2) {
        unsigned e = csr[j];
        float a = aggx[e >> 16];
        float nm = dec_nm(e);
#pragma unroll
        for (int c = 0; c < 16; ++c)
            acc[c] += nm * fmaxf(a * wa[c] + wb[c], 0.f);
    }
    // combine the two parity streams (bit 2 of tid)
#pragma unroll
    for (int c = 0; c < 16; ++c) acc[c] += __shfl_xor(acc[c], 4);
    if (par == 0) {
        float di = dinv[node];
        float d2 = di * di;
        float a = aggx[node];
#pragma unroll
        for (int c = 0; c < 16; ++c)
            acc[c] += d2 * fmaxf(a * wa[c] + wb[c], 0.f);
        uint4 o0, o1;
        unsigned* p0 = &o0.x;
        unsigned* p1 = &o1.x;
#pragma unroll
        for (int j2 = 0; j2 < 4; ++j2) {
            __half2 q0 = __floats2half2_rn(acc[2 * j2], acc[2 * j2 + 1]);
            __half2 q1 = __floats2half2_rn(acc[8 + 2 * j2], acc[8 + 2 * j2 + 1]);
            p0[j2] = *(unsigned*)&q0;
            p1[j2] = *(unsigned*)&q1;
        }
        *(uint4*)(aggs + (size_t)node * 32 + c0) = o0;                          // slice 0
        *(uint4*)(aggs + (size_t)n * 32 + (size_t)node * 32 + c0) = o1;         // slice 1
    }
}

// ---------------------------------------------------------------------------
// Channel-sliced gather from an fp16 node-major-32 table (R4 layout: one
// fully-utilized 64B line per edge per slice). SLB = log2(#slices).
// R10-proven form: 8 thr/node, 4 q x 2 parity, 4/2/1-edge unroll ladder.
template <int SLB>
__global__ void k_gatherS(const int* __restrict__ offs, const unsigned* __restrict__ csr,
                          const __half* __restrict__ Hh, const float* __restrict__ dinv,
                          __half* __restrict__ aggs, int n) {
    int slice = blockIdx.x & ((1 << SLB) - 1);
    int tid = threadIdx.x;
    int node = (blockIdx.x >> SLB) * 32 + (tid >> 3);
    if (node >= n) return;
    int q = tid & 3;
    int par = (tid >> 2) & 1;
    const __half* Hb = Hh + (size_t)slice * ((size_t)n * 32) + q * 8;
    float acc[8] = {0.f, 0.f, 0.f, 0.f, 0.f, 0.f, 0.f, 0.f};
    int e0 = offs[node], e1 = offs[node + 1];
    int j = e0 + par;
#define GS_LOAD(ev, rawv) uint4 rawv = *(const uint4*)(Hb + (size_t)((ev) >> 16) * 32)
#define GS_ACC(rawv, nmv) { \
        __half2 h0 = *(__half2*)&rawv.x; __half2 h1 = *(__half2*)&rawv.y; \
        __half2 h2 = *(__half2*)&rawv.z; __half2 h3 = *(__half2*)&rawv.w; \
        float2 f0 = __half22float2(h0); float2 f1 = __half22float2(h1); \
        float2 f2 = __half22float2(h2); float2 f3 = __half22float2(h3); \
        acc[0] += f0.x * nmv; acc[1] += f0.y * nmv; \
        acc[2] += f1.x * nmv; acc[3] += f1.y * nmv; \
        acc[4] += f2.x * nmv; acc[5] += f2.y * nmv; \
        acc[6] += f3.x * nmv; acc[7] += f3.y * nmv; }
    // 4-edge unroll within this parity stream (stride 2)
    for (; j + 6 < e1; j += 8) {
        unsigned e_0 = csr[j];
        unsigned e_1 = csr[j + 2];
        unsigned e_2 = csr[j + 4];
        unsigned e_3 = csr[j + 6];
        GS_LOAD(e_0, r0); GS_LOAD(e_1, r1); GS_LOAD(e_2, r2); GS_LOAD(e_3, r3);
        GS_ACC(r0, dec_nm(e_0)); GS_ACC(r1, dec_nm(e_1));
        GS_ACC(r2, dec_nm(e_2)); GS_ACC(r3, dec_nm(e_3));
    }
    // 2-edge step (common case for the ~6.4-edge streams)
    for (; j + 2 < e1; j += 4) {
        unsigned e_0 = csr[j];
        unsigned e_1 = csr[j + 2];
        GS_LOAD(e_0, r0); GS_LOAD(e_1, r1);
        GS_ACC(r0, dec_nm(e_0)); GS_ACC(r1, dec_nm(e_1));
    }
    for (; j < e1; j += 2) {
        unsigned e = csr[j];
        GS_LOAD(e, rr);
        GS_ACC(rr, dec_nm(e));
    }
    // combine the two parity streams (bit 2 of tid)
#pragma unroll
    for (int k = 0; k < 8; ++k) acc[k] += __shfl_xor(acc[k], 4);
    if (par == 0) {
        float di = dinv[node];
        float d2 = di * di;
        GS_LOAD((unsigned)node << 16, rs);
        GS_ACC(rs, d2);
        uint4 ov;
        unsigned* op4 = &ov.x;
#pragma unroll
        for (int j2 = 0; j2 < 4; ++j2) {
            __half2 p = __floats2half2_rn(acc[2 * j2], acc[2 * j2 + 1]);
            op4[j2] = *(unsigned*)&p;
        }
        *(uint4*)(aggs + (size_t)slice * ((size_t)n * 32) + (size_t)node * 32 + q * 8) = ov;
    }
#undef GS_LOAD
#undef GS_ACC
}

// ---------------------------------------------------------------------------
// MFMA matmul (f16 16x16x32): 64 nodes/block, 4 waves, wave = one 16-node
// m-tile x all 8 ch-tiles, K = KS*32. A-frags direct from the gather table
// ([kstep][node][32]); B-frags pre-swizzled. C/D: col=lane&15,
// row=(lane>>4)*4+reg [HW-verified, R5]. BN+ReLU epilogue; per-graph pooling
// into sums. WRT=1 additionally writes the fp16 node-major-32 table (layer 2).
template <int KS, int WRT>
__global__ __launch_bounds__(256) void k_mmF(
    const __half* __restrict__ aggs, const __half* __restrict__ Ws,
    const float* __restrict__ kA, const float* __restrict__ kB,
    const int* __restrict__ batch, float* __restrict__ sums,
    __half* __restrict__ outh, int n) {
    const size_t N32 = (size_t)n * 32;
    int base = blockIdx.x * 64;
    int tid = threadIdx.x;
    int w = tid >> 6;
    int l = tid & 63;
    int lr = l & 15;
    int lg = l >> 4;
    int anode = base + w * 16 + lr;
    if (anode > n - 1) anode = n - 1;   // clamped (OOB rows excluded below)
    const __half* ap = aggs + (size_t)anode * 32 + lg * 8;
    f16x8 afr[KS];
#pragma unroll
    for (int ks = 0; ks < KS; ++ks)
        afr[ks] = *(const f16x8*)(ap + (size_t)ks * N32);

    const f16x8* Wv = (const f16x8*)Ws;
    f32x4 acc[8];
#pragma unroll
    for (int nt = 0; nt < 8; ++nt) acc[nt] = (f32x4){0.f, 0.f, 0.f, 0.f};
#pragma unroll
    for (int nt = 0; nt < 8; ++nt) {
#pragma unroll
        for (int ks = 0; ks < KS; ++ks) {
            f16x8 bfr = Wv[(size_t)(nt * KS + ks) * 64 + l];
            acc[nt] = __builtin_amdgcn_mfma_f32_16x16x32_f16(afr[ks], bfr, acc[nt], 0, 0, 0);
        }
    }
    // epilogue: BN + ReLU
    int pnode0 = base + w * 16 + lg * 4;
    int bgv[4];
#pragma unroll
    for (int r = 0; r < 4; ++r) {
        int nd = pnode0 + r;
        bgv[r] = (nd < n) ? batch[nd] : -1;
    }
    float h[8][4];
#pragma unroll
    for (int nt = 0; nt < 8; ++nt) {
        int ch = nt * 16 + lr;
        float ka = kA[ch], kb = kB[ch];
#pragma unroll
        for (int r = 0; r < 4; ++r)
            h[nt][r] = fmaxf(acc[nt][r] * ka + kb, 0.f);
    }
    if (WRT) {
#pragma unroll
        for (int nt = 0; nt < 8; ++nt) {
            int ch = nt * 16 + lr;
            size_t sbase = (size_t)(ch >> 5) * N32 + (ch & 31);
#pragma unroll
            for (int r = 0; r < 4; ++r) {
                int nd = pnode0 + r;
                if (nd < n) outh[sbase + (size_t)nd * 32] = (__half)h[nt][r];
            }
        }
    }
    // per-graph pooling
    __shared__ float pred[4][128];
    int g0 = batch[base];
    int gl = batch[(base + 63 < n) ? (base + 63) : (n - 1)];
    for (int g = g0; g <= gl; ++g) {
        __syncthreads();
#pragma unroll
        for (int nt = 0; nt < 8; ++nt) {
            float s = 0.f;
#pragma unroll
            for (int r = 0; r < 4; ++r)
                if (bgv[r] == g) s += h[nt][r];
            s += __shfl_xor(s, 16);
            s += __shfl_xor(s, 32);
            if (l < 16) pred[w][nt * 16 + l] = s;
        }
        __syncthreads();
        if (tid < 128) {
            float tot = pred[0][tid] + pred[1][tid] + pred[2][tid] + pred[3][tid];
            atomicAdd(&sums[g * 128 + tid], tot);
        }
    }
}

// ---------------------------------------------------------------------------
// Finalize: out[g] = dot(sums[g]/cnt[g], Wf) + bf. 256KB read — trivial.
__global__ __launch_bounds__(128) void k_final(
    const float* __restrict__ sums, const int* __restrict__ goffs,
    const float* __restrict__ Wf, const float* __restrict__ bf,
    float* __restrict__ out) {
    int g = blockIdx.x;
    int t = threadIdx.x;
    float v = sums[g * 128 + t] * Wf[t];
    for (int o = 32; o > 0; o >>= 1) v += __shfl_down(v, o);
    __shared__ float r[2];
    if (t == 0) r[0] = v;
    if (t == 64) r[1] = v;
    __syncthreads();
    if (t == 0) {
        int cnt = goffs[g + 1] - goffs[g];
        out[g] = (r[0] + r[1]) / fmaxf((float)cnt, 1.f) + bf[0];
    }
}

// ---------------------------------------------------------------------------
extern "C" void kernel_launch(void* const* d_in, const int* in_sizes, int n_in,
                              void* d_out, int out_size, void* d_ws, size_t ws_size,
                              hipStream_t stream) {
    const float* x     = (const float*)d_in[0];
    const int*   ei    = (const int*)d_in[1];
    const int*   src   = ei;
    const int*   dst   = ei + N_EDGES;
    const float* w     = (const float*)d_in[2];
    const int*   batch = (const int*)d_in[3];
    const float* W1 = (const float*)d_in[4];
    const float* b1 = (const float*)d_in[5];
    const float* W2 = (const float*)d_in[6];
    const float* b2 = (const float*)d_in[7];
    const float* W3 = (const float*)d_in[8];
    const float* b3 = (const float*)d_in[9];
    const float* Wf = (const float*)d_in[10];
    const float* bf = (const float*)d_in[11];
    const float* g1 = (const float*)d_in[12];
    const float* be1 = (const float*)d_in[13];
    const float* m1 = (const float*)d_in[14];
    const float* v1 = (const float*)d_in[15];
    const float* g2 = (const float*)d_in[16];
    const float* be2 = (const float*)d_in[17];
    const float* m2 = (const float*)d_in[18];
    const float* v2 = (const float*)d_in[19];
    const float* g3 = (const float*)d_in[20];
    const float* be3 = (const float*)d_in[21];
    const float* m3 = (const float*)d_in[22];
    const float* v3 = (const float*)d_in[23];

    float* out = (float*)d_out;

    // Workspace layout
    float* ws    = (float*)d_ws;
    float* buf2  = ws;                                    // N*128 fp32-sized region:
    __half* agg2h = (__half*)buf2;                        // N*64 fp16 (6.4MB)
    __half* aggsh = (__half*)((char*)buf2 + (size_t)N_NODES * 64 * 2);   // N*128 fp16 (12.8MB)
    unsigned* csr = (unsigned*)(buf2 + (size_t)N_NODES * 128); // E uint
    unsigned long long* packed = (unsigned long long*)(csr + N_EDGES); // N ull
    float* sums  = (float*)(packed + N_NODES);            // G*128
    unsigned long long* state = (unsigned long long*)(sums + N_GRAPHS * 128); // SCAN_NB ull
    unsigned* ticket = (unsigned*)(state + SCAN_NB);      // 4 uint (pad)
    int*   seq   = (int*)(ticket + 4);                    // E
    float* dinv  = (float*)(seq + N_EDGES);               // N
    float* aggx  = dinv + N_NODES;                        // N fp32
    float* kA1   = aggx + N_NODES;                        // 64
    float* kB1   = kA1 + 64;                              // 64
    float* kA2   = kB1 + 64;                              // 128
    float* kB2   = kA2 + 128;                             // 128
    float* kA3   = kB2 + 128;                             // 128
    float* kB3   = kA3 + 128;                             // 128
    int*   offs  = (int*)(kB3 + 128);                     // N+1
    int*   goffs = offs + N_NODES + 1;                    // G+1 (+pad)
    // out2h: N*128 fp16 table, 64B-aligned so each 64B node-row is one line
    uintptr_t oh = (uintptr_t)(goffs + 505);
    oh = (oh + 63) & ~(uintptr_t)63;
    __half* out2h = (__half*)oh;                          // 12.8 MB
    __half* W3s   = out2h + (size_t)N_NODES * 128;        // 32 KB
    __half* W2s   = W3s + 2048 * 8;                       // 16 KB

    const int BS = 256;
    auto nb = [](long n) { return (int)((n + 255) / 256); };

    // zero packed + sums + state + ticket in one call (contiguous in ws)
    size_t ms_bytes = (size_t)N_NODES * 8 + (size_t)N_GRAPHS * 128 * 4
                    + (size_t)SCAN_NB * 8 + 16;
    hipMemsetAsync(packed, 0, ms_bytes, stream);

    // --- CSR build + degree norm (+goffs+bnprep+W2/W3 swizzle in scanF) ---
    k_degcnt<<<nb(N_EDGES), BS, 0, stream>>>(dst, w, packed, seq, N_EDGES);
    k_scanF<<<SCAN_NB, 256, 0, stream>>>(packed, state, ticket, offs, dinv, batch, goffs,
                                         W1, b1, g1, be1, m1, v1, b2, g2, be2, m2, v2,
                                         b3, g3, be3, m3, v3,
                                         kA1, kB1, kA2, kB2, kA3, kB3,
                                         W3, W3s, W2, W2s, N_NODES);
    k_fill<<<nb(N_EDGES), BS, 0, stream>>>(src, dst, w, dinv, offs, seq, csr, N_EDGES);

    // --- Layer 1: aggregate (4 lanes/node) -> fp32 aggx (200KB, L2-hot) ---
    k_aggx<<<nb((long)N_NODES * 4), BS, 0, stream>>>(
        offs, csr, x, dinv, aggx, N_NODES);

    // --- Layer 2: scalar-aggx gather + in-reg h1 (8thr/node) -> fp16
    //     A-frags, MFMA matmul (out2h table + residual pool into sums) ---
    k_gather2A<<<(N_NODES + 31) / 32, BS, 0, stream>>>(
        offs, csr, aggx, dinv, kA1, kB1, agg2h, N_NODES);
    k_mmF<2, 1><<<(N_NODES + 63) / 64, BS, 0, stream>>>(
        agg2h, W2s, kA2, kB2, batch, sums, out2h, N_NODES);

    // --- Layer 3: gather out2h (4 slices, 8thr/node) -> fp16 A-frags,
    //     MFMA matmul + pool ---
    k_gatherS<2><<<4 * ((N_NODES + 31) / 32), BS, 0, stream>>>(
        offs, csr, out2h, dinv, aggsh, N_NODES);
    k_mmF<4, 0><<<(N_NODES + 63) / 64, BS, 0, stream>>>(
        aggsh, W3s, kA3, kB3, batch, sums, nullptr, N_NODES);

    // --- finalize: tiny dot-product over sums ---
    k_final<<<N_GRAPHS, 128, 0, stream>>>(sums, goffs, Wf, bf, out);
}